// Round 10
// baseline (348.024 us; speedup 1.0000x reference)
//
#include <hip/hip_runtime.h>

// GCN 3-layer forward on gfx950.
// Round 22: R21 with compile fix — __builtin_nontemporal_load rejects HIP's
// class-type int4; use ext_vector_type(4) int instead (same dwordx4 load).
//  - Unfused fill (R20 fusion failed: LDS capped occupancy at 37%).
//  - fill: nt edge loads so the 51MB replicated edge stream doesn't evict
//    dirty pairs lines from L2 -> slot-stores merge before writeback
//    (R19/R21 counters: WRITE 48.6MB vs 7.2MB payload = ~7x re-eviction).
//  - gather: persistent grid-stride waves + cross-row pipelining (next row's
//    rowstart early, last prefetch slot = next row's first pairs batch).
// CSR build (8-pad incl self edge), W-conv in cnt kernel, GEMM unchanged.

#define IN_CH 128

typedef __attribute__((ext_vector_type(8))) short bf16x8;
typedef __attribute__((ext_vector_type(4))) float f32x4;
typedef __attribute__((ext_vector_type(4))) int i32x4;

__device__ inline unsigned short f2bf_rne(float f) {
    unsigned u = __float_as_uint(f);
    unsigned r = (u + 0x7FFFu + ((u >> 16) & 1u)) >> 16;
    return (unsigned short)r;
}
__device__ inline float bf2f(unsigned short h) {
    return __uint_as_float(((unsigned)h) << 16);
}
__device__ inline float bf2f_lo(unsigned m) {
    return __uint_as_float(m << 16);
}
__device__ inline float bf2f_hi(unsigned m) {
    return __uint_as_float(m & 0xffff0000u);
}

// ---------------- degree count + W conversion (independent work fused) -----
__device__ inline void convw_one(const float* W, unsigned short* hi, int FOUT, int id) {
    int n = id >> 7, k = id & 127;
    hi[id] = f2bf_rne(W[k * FOUT + n]);
}

__global__ __launch_bounds__(256) void cntconv_k(
    const int* __restrict__ dst, int* __restrict__ cnt, int E, int cntBlocks,
    const float* __restrict__ W1, const float* __restrict__ W2,
    const float* __restrict__ W3,
    unsigned short* __restrict__ W1h, unsigned short* __restrict__ W2h,
    unsigned short* __restrict__ W3h) {
    if ((int)blockIdx.x < cntBlocks) {
        int e = blockIdx.x * 256 + threadIdx.x;
        if (e < E) {
            int d = __builtin_nontemporal_load(dst + e);
            atomicAdd(&cnt[d], 1);
        }
    } else {
        int id = (blockIdx.x - cntBlocks) * 256 + threadIdx.x;
        if (id < 16384) convw_one(W1, W1h, 128, id);
        else if (id < 32768) convw_one(W2, W2h, 128, id - 16384);
        else if (id < 40960) convw_one(W3, W3h, 64, id - 32768);
    }
}

// ---------------- scan stage 1 on PADDED counts (+ dinv from real) --------
// padded count includes the self edge: (cnt+1 rounded up to 8)
__global__ __launch_bounds__(256) void scan1_k(const int* __restrict__ cnt,
                                               int* __restrict__ bsum,
                                               float* __restrict__ dinv, int N) {
    __shared__ int s[256];
    int tid = threadIdx.x;
    int i = blockIdx.x * 256 + tid;
    int vr = (i < N) ? cnt[i] : 0;
    if (i < N) dinv[i] = rsqrtf((float)vr + 1.0f);
    s[tid] = (i < N) ? ((vr + 8) & ~7) : 0;  // self edge + pad to 8
    __syncthreads();
    for (int off = 128; off > 0; off >>= 1) {
        if (tid < off) s[tid] += s[tid + off];
        __syncthreads();
    }
    if (tid == 0) bsum[blockIdx.x] = s[0];
}

__global__ __launch_bounds__(512) void scan2_k(int* __restrict__ bsum, int nb) {
    __shared__ int s[512];
    __shared__ int carry_s;
    int tid = threadIdx.x;
    if (tid == 0) carry_s = 0;
    __syncthreads();
    for (int base = 0; base < nb; base += 512) {
        int c = carry_s;
        int i = base + tid;
        int v = (i < nb) ? bsum[i] : 0;
        s[tid] = v;
        __syncthreads();
        for (int off = 1; off < 512; off <<= 1) {
            int t = (tid >= off) ? s[tid - off] : 0;
            __syncthreads();
            s[tid] += t;
            __syncthreads();
        }
        if (i < nb) bsum[i] = s[tid] - v + c;
        __syncthreads();
        if (tid == 0) carry_s = c + s[511];
        __syncthreads();
    }
}

// scan3: padded exclusive scan -> rowstart[N+1] (preserved) + cur[N] (cursor)
__global__ __launch_bounds__(256) void scan3_k(const int* __restrict__ cnt,
                                               const int* __restrict__ bsum,
                                               int* __restrict__ rowstart,
                                               int* __restrict__ cur, int N) {
    __shared__ int s[256];
    int tid = threadIdx.x;
    int i = blockIdx.x * 256 + tid;
    int v = (i < N) ? ((cnt[i] + 8) & ~7) : 0;
    s[tid] = v;
    __syncthreads();
    for (int off = 1; off < 256; off <<= 1) {
        int t = (tid >= off) ? s[tid - off] : 0;
        __syncthreads();
        s[tid] += t;
        __syncthreads();
    }
    if (i < N) {
        int st = s[tid] - v + bsum[blockIdx.x];
        rowstart[i] = st;
        cur[i] = st;
        if (i == N - 1) rowstart[N] = st + v;
    }
}

// ---------------- fill (CSR pairs + self edges), nt edge loads -------------
// Edge section partitioned: 8 replicated passes; block b keeps edges with dst
// in range (b & 7). Edge streams loaded non-temporally so they don't evict
// the dirty pairs lines from L2 (store-merge before writeback).
__global__ __launch_bounds__(256) void fill_conv_k(
    const int* __restrict__ src, const int* __restrict__ dst,
    const float* __restrict__ dinv, int* __restrict__ cur,
    int2* __restrict__ pairs, int E, int N, int fillBlocks, int selfBlocks,
    int rangeSz) {
    if ((int)blockIdx.x < fillBlocks) {
        const int range = blockIdx.x & 7;           // ~= XCD id
        const int lo = range * rangeSz;
        const int hi = lo + rangeSz;
        const int e0 = (blockIdx.x >> 3) * 1024 + threadIdx.x * 4;
        if (e0 >= E) return;
        int s[4], d[4];
        if (e0 + 4 <= E) {
            i32x4 s4 = __builtin_nontemporal_load((const i32x4*)(src + e0));
            i32x4 d4 = __builtin_nontemporal_load((const i32x4*)(dst + e0));
            s[0] = s4.x; s[1] = s4.y; s[2] = s4.z; s[3] = s4.w;
            d[0] = d4.x; d[1] = d4.y; d[2] = d4.z; d[3] = d4.w;
        } else {
#pragma unroll
            for (int k = 0; k < 4; ++k) {
                s[k] = (e0 + k < E) ? src[e0 + k] : 0;
                d[k] = (e0 + k < E) ? dst[e0 + k] : -1;  // never in range
            }
        }
#pragma unroll
        for (int k = 0; k < 4; ++k) {
            if (d[k] >= lo && d[k] < hi) {
                float nrm = dinv[s[k]] * dinv[d[k]];
                int pos = atomicAdd(&cur[d[k]], 1);
                pairs[pos] = make_int2(s[k] * 256, __float_as_int(nrm));  // byte offset
            }
        }
    } else {
        // self edges: one per node, norm = dinv^2
        int i = (blockIdx.x - fillBlocks) * 256 + threadIdx.x;
        if (i < N) {
            float di = dinv[i];
            int pos = atomicAdd(&cur[i], 1);
            pairs[pos] = make_int2(i * 256, __float_as_int(di * di));
        }
    }
}

// ---------------- MFMA GEMM: T[N][FOUT] = A[N][128] @ W[128][FOUT] ----------
__device__ inline bf16x8 cvt8(const float* __restrict__ p) {
    float4 v0 = *(const float4*)p;
    float4 v1 = *(const float4*)(p + 4);
    bf16x8 h;
    h[0] = (short)f2bf_rne(v0.x); h[1] = (short)f2bf_rne(v0.y);
    h[2] = (short)f2bf_rne(v0.z); h[3] = (short)f2bf_rne(v0.w);
    h[4] = (short)f2bf_rne(v1.x); h[5] = (short)f2bf_rne(v1.y);
    h[6] = (short)f2bf_rne(v1.z); h[7] = (short)f2bf_rne(v1.w);
    return h;
}

template <int FOUT, bool AF32>
__global__ __launch_bounds__(256) void mfma_gemm(const float* __restrict__ Af,
                                                 const unsigned short* __restrict__ Ahi,
                                                 const unsigned short* __restrict__ Bhi,
                                                 unsigned short* __restrict__ Thi,
                                                 int N) {
    constexpr int NCT = FOUT / 16;
    constexpr int BSTRIDE = 136;
    constexpr int CSTRIDE = FOUT + 8;
    constexpr int BU = FOUT * BSTRIDE;
    constexpr int CU2 = 64 * CSTRIDE;
    constexpr int SMEMU = (BU > CU2) ? BU : CU2;
    __shared__ unsigned short smem[SMEMU];

    const int tid = threadIdx.x;
    const int wv = tid >> 6, lane = tid & 63;
    const int quad = lane >> 4, l16 = lane & 15;
    const int row0 = blockIdx.x * 64 + wv * 16;

#pragma unroll
    for (int it = 0; it < FOUT / 16; ++it) {
        int i = it * 256 + tid;
        int r = i >> 4, c = (i & 15) * 8;
        *(bf16x8*)(&smem[r * BSTRIDE + c]) = *(const bf16x8*)(Bhi + (size_t)r * 128 + c);
    }
    __syncthreads();

    f32x4 acc[NCT];
#pragma unroll
    for (int ct = 0; ct < NCT; ++ct)
        acc[ct] = (f32x4){0.f, 0.f, 0.f, 0.f};

    const int ra = AF32 ? min(row0 + l16, N - 1) : (row0 + l16);

#pragma unroll
    for (int ks = 0; ks < 4; ++ks) {
        const int ko = ks * 32 + quad * 8;
        bf16x8 ah;
        if (AF32) {
            ah = cvt8(Af + (size_t)ra * 128 + ko);
        } else {
            ah = *(const bf16x8*)(Ahi + (size_t)ra * 128 + ko);
        }
#pragma unroll
        for (int ct = 0; ct < NCT; ++ct) {
            bf16x8 bh = *(const bf16x8*)(&smem[(ct * 16 + l16) * BSTRIDE + ko]);
            acc[ct] = __builtin_amdgcn_mfma_f32_16x16x32_bf16(ah, bh, acc[ct], 0, 0, 0);
        }
    }

    __syncthreads();
    const int lrow = wv * 16 + quad * 4;
#pragma unroll
    for (int ct = 0; ct < NCT; ++ct) {
        const int col = ct * 16 + l16;
#pragma unroll
        for (int r = 0; r < 4; ++r)
            smem[(lrow + r) * CSTRIDE + col] = f2bf_rne(acc[ct][r]);
    }
    __syncthreads();
    constexpr int CH = FOUT / 8;
#pragma unroll
    for (int i = 0; i < 64 * CH / 256; ++i) {
        int ci = i * 256 + tid;
        int r = ci / CH, c = (ci % CH) * 8;
        int grow = blockIdx.x * 64 + r;
        if (grow < N)
            *(uint4*)(Thi + (size_t)grow * FOUT + c) = *(const uint4*)&smem[r * CSTRIDE + c];
    }
}

// ---------------- gather: persistent waves, row-pipelined, 8-unrolled ------
// res[row] = b + sum_e norm_e * Thi@off_e  (self edge included in pairs)
// Rows padded to 8-multiples (>=1 iter/row). Wave walks rows gw, gw+GW, ...
// Next row's rowstart issued before current row's edge loop; edge loop's
// last prefetch slot loads the next row's first pairs batch.
struct Pairs4 { int4 p0, p1, p2, p3; };

__device__ inline Pairs4 ldpairs(const int2* __restrict__ pairs, int j) {
    Pairs4 r;
    r.p0 = *(const int4*)(pairs + j);
    r.p1 = *(const int4*)(pairs + j + 2);
    r.p2 = *(const int4*)(pairs + j + 4);
    r.p3 = *(const int4*)(pairs + j + 6);
    return r;
}

__device__ inline void ldrows128(const char* __restrict__ tbase, int laneB,
                                 const Pairs4& P, unsigned m[8]) {
    m[0] = *(const unsigned*)(tbase + (unsigned)P.p0.x + laneB);
    m[1] = *(const unsigned*)(tbase + (unsigned)P.p0.z + laneB);
    m[2] = *(const unsigned*)(tbase + (unsigned)P.p1.x + laneB);
    m[3] = *(const unsigned*)(tbase + (unsigned)P.p1.z + laneB);
    m[4] = *(const unsigned*)(tbase + (unsigned)P.p2.x + laneB);
    m[5] = *(const unsigned*)(tbase + (unsigned)P.p2.z + laneB);
    m[6] = *(const unsigned*)(tbase + (unsigned)P.p3.x + laneB);
    m[7] = *(const unsigned*)(tbase + (unsigned)P.p3.z + laneB);
}

__device__ inline void fma8_128(const Pairs4& P, const unsigned m[8],
                                float& ax, float& ay) {
    float n0 = __int_as_float(P.p0.y), n1 = __int_as_float(P.p0.w);
    float n2 = __int_as_float(P.p1.y), n3 = __int_as_float(P.p1.w);
    float n4 = __int_as_float(P.p2.y), n5 = __int_as_float(P.p2.w);
    float n6 = __int_as_float(P.p3.y), n7 = __int_as_float(P.p3.w);
    ax += n0 * bf2f_lo(m[0]); ay += n0 * bf2f_hi(m[0]);
    ax += n1 * bf2f_lo(m[1]); ay += n1 * bf2f_hi(m[1]);
    ax += n2 * bf2f_lo(m[2]); ay += n2 * bf2f_hi(m[2]);
    ax += n3 * bf2f_lo(m[3]); ay += n3 * bf2f_hi(m[3]);
    ax += n4 * bf2f_lo(m[4]); ay += n4 * bf2f_hi(m[4]);
    ax += n5 * bf2f_lo(m[5]); ay += n5 * bf2f_hi(m[5]);
    ax += n6 * bf2f_lo(m[6]); ay += n6 * bf2f_hi(m[6]);
    ax += n7 * bf2f_lo(m[7]); ay += n7 * bf2f_hi(m[7]);
}

__device__ inline void ldrows64(const char* __restrict__ tbase, int laneB,
                                const Pairs4& P, float m[8]) {
    m[0] = bf2f(*(const unsigned short*)(tbase + ((unsigned)P.p0.x >> 1) + laneB));
    m[1] = bf2f(*(const unsigned short*)(tbase + ((unsigned)P.p0.z >> 1) + laneB));
    m[2] = bf2f(*(const unsigned short*)(tbase + ((unsigned)P.p1.x >> 1) + laneB));
    m[3] = bf2f(*(const unsigned short*)(tbase + ((unsigned)P.p1.z >> 1) + laneB));
    m[4] = bf2f(*(const unsigned short*)(tbase + ((unsigned)P.p2.x >> 1) + laneB));
    m[5] = bf2f(*(const unsigned short*)(tbase + ((unsigned)P.p2.z >> 1) + laneB));
    m[6] = bf2f(*(const unsigned short*)(tbase + ((unsigned)P.p3.x >> 1) + laneB));
    m[7] = bf2f(*(const unsigned short*)(tbase + ((unsigned)P.p3.z >> 1) + laneB));
}

__device__ inline void fma8_64(const Pairs4& P, const float m[8], float& acc) {
    acc += __int_as_float(P.p0.y) * m[0] + __int_as_float(P.p0.w) * m[1] +
           __int_as_float(P.p1.y) * m[2] + __int_as_float(P.p1.w) * m[3] +
           __int_as_float(P.p2.y) * m[4] + __int_as_float(P.p2.w) * m[5] +
           __int_as_float(P.p3.y) * m[6] + __int_as_float(P.p3.w) * m[7];
}

template <int FOUT, bool SPLIT>
__global__ __launch_bounds__(256) void gather_k(const int* __restrict__ rowstart,
                                                const int2* __restrict__ pairs,
                                                const unsigned short* __restrict__ Thi,
                                                const float* __restrict__ bias,
                                                float* __restrict__ out,
                                                unsigned short* __restrict__ outHi,
                                                int N) {
    const int wave = threadIdx.x >> 6;
    const int lane = threadIdx.x & 63;
    const int GW = gridDim.x * 4;
    int row = blockIdx.x * 4 + wave;
    if (row >= N) return;
    const char* tbase = (const char*)Thi;

    int sC = rowstart[row];
    int eC = rowstart[row + 1];
    Pairs4 P = ldpairs(pairs, sC);

    if (FOUT == 128) {
        const int laneB = lane * 4;
        const float2 bb = *(const float2*)(bias + lane * 2);
        for (;;) {
            const int nrow = row + GW;
            const bool hasN = nrow < N;
            int sN = sC, eN = eC;
            if (hasN) { sN = rowstart[nrow]; eN = rowstart[nrow + 1]; }
            float ax = bb.x, ay = bb.y;
            int j = sC;
            for (;;) {
                unsigned m[8];
                ldrows128(tbase, laneB, P, m);
                j += 8;
                const bool more = j < eC;
                const int pj = more ? j : sN;  // next batch or next row's first
                Pairs4 Q = ldpairs(pairs, pj);
                fma8_128(P, m, ax, ay);
                P = Q;
                if (!more) break;
            }
            if (SPLIT) {
                ushort2 h;
                h.x = f2bf_rne(fmaxf(ax, 0.f));
                h.y = f2bf_rne(fmaxf(ay, 0.f));
                *(ushort2*)(outHi + (size_t)row * 128 + lane * 2) = h;
            } else {
                float2 o; o.x = ax; o.y = ay;
                *(float2*)(out + (size_t)row * 128 + lane * 2) = o;
            }
            if (!hasN) break;
            row = nrow; sC = sN; eC = eN;
        }
    } else {  // FOUT == 64: rows are 128B; byte offset = off>>1
        const int laneB = lane * 2;
        const float bb = bias[lane];
        for (;;) {
            const int nrow = row + GW;
            const bool hasN = nrow < N;
            int sN = sC, eN = eC;
            if (hasN) { sN = rowstart[nrow]; eN = rowstart[nrow + 1]; }
            float acc = bb;
            int j = sC;
            for (;;) {
                float m[8];
                ldrows64(tbase, laneB, P, m);
                j += 8;
                const bool more = j < eC;
                const int pj = more ? j : sN;
                Pairs4 Q = ldpairs(pairs, pj);
                fma8_64(P, m, acc);
                P = Q;
                if (!more) break;
            }
            out[(size_t)row * FOUT + lane] = acc;
            if (!hasN) break;
            row = nrow; sC = sN; eC = eN;
        }
    }
}

extern "C" void kernel_launch(void* const* d_in, const int* in_sizes, int n_in,
                              void* d_out, int out_size, void* d_ws, size_t ws_size,
                              hipStream_t stream) {
    const float* x  = (const float*)d_in[0];
    const int* eidx = (const int*)d_in[1];
    const float* W1 = (const float*)d_in[2];
    const float* b1 = (const float*)d_in[3];
    const float* W2 = (const float*)d_in[4];
    const float* b2 = (const float*)d_in[5];
    const float* W3 = (const float*)d_in[6];
    const float* b3 = (const float*)d_in[7];
    float* out = (float*)d_out;

    const int N = in_sizes[0] / IN_CH;
    const int E = in_sizes[1] / 2;
    const int* src = eidx;
    const int* dst = eidx + E;
    const int Npad = ((N + 127) / 128) * 128;
    const int nb = (N + 255) / 256;
    const int Emax = E + 8 * N + 24;  // self edges + 8-pad + prefetch slack

    auto align = [](size_t v) { return (v + 255) / 256 * 256; };
    char* p = (char*)d_ws;
    int* cnt = (int*)p;            p += align((size_t)N * 4);
    int* rowstart = (int*)p;       p += align((size_t)(N + 1) * 4);
    int* cur = (int*)p;            p += align((size_t)N * 4);
    int* bsum = (int*)p;           p += align((size_t)nb * 4);
    float* dinv = (float*)p;       p += align((size_t)N * 4);
    int2* pairs = (int2*)p;        p += align((size_t)Emax * 8);
    unsigned short* Ahi = (unsigned short*)p;  p += align((size_t)Npad * 128 * 2);
    unsigned short* Thi = (unsigned short*)p;  p += align((size_t)Npad * 128 * 2);
    unsigned short* W1h = (unsigned short*)p;  p += align(128 * 128 * 2);
    unsigned short* W2h = (unsigned short*)p;  p += align(128 * 128 * 2);
    unsigned short* W3h = (unsigned short*)p;

    // ---- CSR build (once; reused by all 3 layers) ----
    hipMemsetAsync(cnt, 0, (size_t)N * 4, stream);
    hipMemsetAsync(pairs, 0, (size_t)Emax * 8, stream);  // pad edges = (0,0)
    const int cntBlocks = (E + 255) / 256;
    cntconv_k<<<cntBlocks + 160, 256, 0, stream>>>(dst, cnt, E, cntBlocks,
                                                   W1, W2, W3, W1h, W2h, W3h);
    scan1_k<<<nb, 256, 0, stream>>>(cnt, bsum, dinv, N);
    scan2_k<<<1, 512, 0, stream>>>(bsum, nb);
    scan3_k<<<nb, 256, 0, stream>>>(cnt, bsum, rowstart, cur, N);

    // partitioned fill: 8 dst-range passes, 4 edges/thread; + self edges
    const int chunks = (E + 1023) / 1024;
    const int fillBlocks = chunks * 8;
    const int selfBlocks = (N + 255) / 256;
    const int rangeSz = (N + 7) / 8;
    fill_conv_k<<<fillBlocks + selfBlocks, 256, 0, stream>>>(
        src, dst, dinv, cur, pairs, E, N, fillBlocks, selfBlocks, rangeSz);

    const int gemm_blocks = (N + 63) / 64;
    const int gather_blocks = min(2048, (N + 3) / 4);

    // Layer 1 (A = x fp32, converted in-register)
    mfma_gemm<128, true><<<gemm_blocks, 256, 0, stream>>>(x, nullptr, W1h, Thi, N);
    gather_k<128, true><<<gather_blocks, 256, 0, stream>>>(rowstart, pairs, Thi,
                                                           b1, nullptr, Ahi, N);
    // Layer 2
    mfma_gemm<128, false><<<gemm_blocks, 256, 0, stream>>>(nullptr, Ahi, W2h, Thi, N);
    gather_k<128, true><<<gather_blocks, 256, 0, stream>>>(rowstart, pairs, Thi,
                                                           b2, nullptr, Ahi, N);
    // Layer 3
    mfma_gemm<64, false><<<gemm_blocks, 256, 0, stream>>>(nullptr, Ahi, W3h, Thi, N);
    gather_k<64, false><<<gather_blocks, 256, 0, stream>>>(rowstart, pairs, Thi,
                                                           b3, out, nullptr, N);
}

// Round 11
// 331.056 us; speedup vs baseline: 1.0513x; 1.0513x over previous
//
#include <hip/hip_runtime.h>

// GCN 3-layer forward on gfx950.
// Round 23: revert R20-R22 experiments (fusion: LDS-capped occupancy; nt-loads:
// write-amp is temporal not capacity — WRITE 48.6->42.2MB only, fill slower;
// persistent gather: no visible win). Base = R19 (330us best: fill 42 w/ fused
// W-conv + self edges, 8-pad CSR).
// NEW: half-wave dual-row gather. Lanes 0-31 = row A, lanes 32-63 = row B,
// 8B/lane (uint2): the SAME 8 load instructions per iteration serve TWO rows
// -> 2x per-wave MLP with no instruction doubling (R18's failure) and ~+16
// VGPR only. Loop runs max(itA,itB); exhausted half predicated (j frozen,
// FMA guarded). Prefetch pipeline kept (1 RT/iter).

#define IN_CH 128

typedef __attribute__((ext_vector_type(8))) short bf16x8;
typedef __attribute__((ext_vector_type(4))) float f32x4;

__device__ inline unsigned short f2bf_rne(float f) {
    unsigned u = __float_as_uint(f);
    unsigned r = (u + 0x7FFFu + ((u >> 16) & 1u)) >> 16;
    return (unsigned short)r;
}
__device__ inline float bf2f(unsigned short h) {
    return __uint_as_float(((unsigned)h) << 16);
}
__device__ inline float bf2f_lo(unsigned m) {
    return __uint_as_float(m << 16);
}
__device__ inline float bf2f_hi(unsigned m) {
    return __uint_as_float(m & 0xffff0000u);
}

// ---------------- degree count ----------------
__global__ __launch_bounds__(256) void cnt_k(const int* __restrict__ dst,
                                             int* __restrict__ cnt, int E) {
    int e = blockIdx.x * 256 + threadIdx.x;
    if (e < E) atomicAdd(&cnt[dst[e]], 1);
}

// ---------------- scan stage 1 on PADDED counts (+ dinv from real) --------
// padded count includes the self edge: (cnt+1 rounded up to 8)
__global__ __launch_bounds__(256) void scan1_k(const int* __restrict__ cnt,
                                               int* __restrict__ bsum,
                                               float* __restrict__ dinv, int N) {
    __shared__ int s[256];
    int tid = threadIdx.x;
    int i = blockIdx.x * 256 + tid;
    int vr = (i < N) ? cnt[i] : 0;
    if (i < N) dinv[i] = rsqrtf((float)vr + 1.0f);
    s[tid] = (i < N) ? ((vr + 8) & ~7) : 0;  // self edge + pad to 8
    __syncthreads();
    for (int off = 128; off > 0; off >>= 1) {
        if (tid < off) s[tid] += s[tid + off];
        __syncthreads();
    }
    if (tid == 0) bsum[blockIdx.x] = s[0];
}

__global__ __launch_bounds__(512) void scan2_k(int* __restrict__ bsum, int nb) {
    __shared__ int s[512];
    __shared__ int carry_s;
    int tid = threadIdx.x;
    if (tid == 0) carry_s = 0;
    __syncthreads();
    for (int base = 0; base < nb; base += 512) {
        int c = carry_s;
        int i = base + tid;
        int v = (i < nb) ? bsum[i] : 0;
        s[tid] = v;
        __syncthreads();
        for (int off = 1; off < 512; off <<= 1) {
            int t = (tid >= off) ? s[tid - off] : 0;
            __syncthreads();
            s[tid] += t;
            __syncthreads();
        }
        if (i < nb) bsum[i] = s[tid] - v + c;
        __syncthreads();
        if (tid == 0) carry_s = c + s[511];
        __syncthreads();
    }
}

// scan3: padded exclusive scan -> rowstart[N+1] (preserved) + cur[N] (cursor)
__global__ __launch_bounds__(256) void scan3_k(const int* __restrict__ cnt,
                                               const int* __restrict__ bsum,
                                               int* __restrict__ rowstart,
                                               int* __restrict__ cur, int N) {
    __shared__ int s[256];
    int tid = threadIdx.x;
    int i = blockIdx.x * 256 + tid;
    int v = (i < N) ? ((cnt[i] + 8) & ~7) : 0;
    s[tid] = v;
    __syncthreads();
    for (int off = 1; off < 256; off <<= 1) {
        int t = (tid >= off) ? s[tid - off] : 0;
        __syncthreads();
        s[tid] += t;
        __syncthreads();
    }
    if (i < N) {
        int st = s[tid] - v + bsum[blockIdx.x];
        rowstart[i] = st;
        cur[i] = st;
        if (i == N - 1) rowstart[N] = st + v;
    }
}

// ---------------- fill (CSR pairs + self edges) + W conversion -------------
// Edge section partitioned: 8 replicated passes; block b keeps edges with dst
// in range (b & 7) (~= XCD under round-robin dispatch).
__device__ inline void convw_one(const float* W, unsigned short* hi, int FOUT, int id) {
    int n = id >> 7, k = id & 127;
    hi[id] = f2bf_rne(W[k * FOUT + n]);
}

__global__ __launch_bounds__(256) void fill_conv_k(
    const int* __restrict__ src, const int* __restrict__ dst,
    const float* __restrict__ dinv, int* __restrict__ cur,
    int2* __restrict__ pairs, int E, int N, int fillBlocks, int selfBlocks,
    int rangeSz,
    const float* __restrict__ W1, const float* __restrict__ W2,
    const float* __restrict__ W3,
    unsigned short* __restrict__ W1h, unsigned short* __restrict__ W2h,
    unsigned short* __restrict__ W3h) {
    if ((int)blockIdx.x < fillBlocks) {
        const int range = blockIdx.x & 7;           // ~= XCD id
        const int lo = range * rangeSz;
        const int hi = lo + rangeSz;
        const int e0 = (blockIdx.x >> 3) * 1024 + threadIdx.x * 4;
        if (e0 >= E) return;
        int s[4], d[4];
        if (e0 + 4 <= E) {
            int4 s4 = *(const int4*)(src + e0);
            int4 d4 = *(const int4*)(dst + e0);
            s[0] = s4.x; s[1] = s4.y; s[2] = s4.z; s[3] = s4.w;
            d[0] = d4.x; d[1] = d4.y; d[2] = d4.z; d[3] = d4.w;
        } else {
#pragma unroll
            for (int k = 0; k < 4; ++k) {
                s[k] = (e0 + k < E) ? src[e0 + k] : 0;
                d[k] = (e0 + k < E) ? dst[e0 + k] : -1;  // never in range
            }
        }
#pragma unroll
        for (int k = 0; k < 4; ++k) {
            if (d[k] >= lo && d[k] < hi) {
                float nrm = dinv[s[k]] * dinv[d[k]];
                int pos = atomicAdd(&cur[d[k]], 1);
                pairs[pos] = make_int2(s[k] * 256, __float_as_int(nrm));  // byte offset
            }
        }
    } else if ((int)blockIdx.x < fillBlocks + selfBlocks) {
        // self edges: one per node, norm = dinv^2
        int i = (blockIdx.x - fillBlocks) * 256 + threadIdx.x;
        if (i < N) {
            float di = dinv[i];
            int pos = atomicAdd(&cur[i], 1);
            pairs[pos] = make_int2(i * 256, __float_as_int(di * di));
        }
    } else {
        int id = (blockIdx.x - fillBlocks - selfBlocks) * 256 + threadIdx.x;
        if (id < 16384) convw_one(W1, W1h, 128, id);
        else if (id < 32768) convw_one(W2, W2h, 128, id - 16384);
        else if (id < 40960) convw_one(W3, W3h, 64, id - 32768);
    }
}

// ---------------- MFMA GEMM: T[N][FOUT] = A[N][128] @ W[128][FOUT] ----------
__device__ inline bf16x8 cvt8(const float* __restrict__ p) {
    float4 v0 = *(const float4*)p;
    float4 v1 = *(const float4*)(p + 4);
    bf16x8 h;
    h[0] = (short)f2bf_rne(v0.x); h[1] = (short)f2bf_rne(v0.y);
    h[2] = (short)f2bf_rne(v0.z); h[3] = (short)f2bf_rne(v0.w);
    h[4] = (short)f2bf_rne(v1.x); h[5] = (short)f2bf_rne(v1.y);
    h[6] = (short)f2bf_rne(v1.z); h[7] = (short)f2bf_rne(v1.w);
    return h;
}

template <int FOUT, bool AF32>
__global__ __launch_bounds__(256) void mfma_gemm(const float* __restrict__ Af,
                                                 const unsigned short* __restrict__ Ahi,
                                                 const unsigned short* __restrict__ Bhi,
                                                 unsigned short* __restrict__ Thi,
                                                 int N) {
    constexpr int NCT = FOUT / 16;
    constexpr int BSTRIDE = 136;
    constexpr int CSTRIDE = FOUT + 8;
    constexpr int BU = FOUT * BSTRIDE;
    constexpr int CU2 = 64 * CSTRIDE;
    constexpr int SMEMU = (BU > CU2) ? BU : CU2;
    __shared__ unsigned short smem[SMEMU];

    const int tid = threadIdx.x;
    const int wv = tid >> 6, lane = tid & 63;
    const int quad = lane >> 4, l16 = lane & 15;
    const int row0 = blockIdx.x * 64 + wv * 16;

#pragma unroll
    for (int it = 0; it < FOUT / 16; ++it) {
        int i = it * 256 + tid;
        int r = i >> 4, c = (i & 15) * 8;
        *(bf16x8*)(&smem[r * BSTRIDE + c]) = *(const bf16x8*)(Bhi + (size_t)r * 128 + c);
    }
    __syncthreads();

    f32x4 acc[NCT];
#pragma unroll
    for (int ct = 0; ct < NCT; ++ct)
        acc[ct] = (f32x4){0.f, 0.f, 0.f, 0.f};

    const int ra = AF32 ? min(row0 + l16, N - 1) : (row0 + l16);

#pragma unroll
    for (int ks = 0; ks < 4; ++ks) {
        const int ko = ks * 32 + quad * 8;
        bf16x8 ah;
        if (AF32) {
            ah = cvt8(Af + (size_t)ra * 128 + ko);
        } else {
            ah = *(const bf16x8*)(Ahi + (size_t)ra * 128 + ko);
        }
#pragma unroll
        for (int ct = 0; ct < NCT; ++ct) {
            bf16x8 bh = *(const bf16x8*)(&smem[(ct * 16 + l16) * BSTRIDE + ko]);
            acc[ct] = __builtin_amdgcn_mfma_f32_16x16x32_bf16(ah, bh, acc[ct], 0, 0, 0);
        }
    }

    __syncthreads();
    const int lrow = wv * 16 + quad * 4;
#pragma unroll
    for (int ct = 0; ct < NCT; ++ct) {
        const int col = ct * 16 + l16;
#pragma unroll
        for (int r = 0; r < 4; ++r)
            smem[(lrow + r) * CSTRIDE + col] = f2bf_rne(acc[ct][r]);
    }
    __syncthreads();
    constexpr int CH = FOUT / 8;
#pragma unroll
    for (int i = 0; i < 64 * CH / 256; ++i) {
        int ci = i * 256 + tid;
        int r = ci / CH, c = (ci % CH) * 8;
        int grow = blockIdx.x * 64 + r;
        if (grow < N)
            *(uint4*)(Thi + (size_t)grow * FOUT + c) = *(const uint4*)&smem[r * CSTRIDE + c];
    }
}

// ---------------- gather: half-wave dual-row, 8-unrolled + prefetch --------
// res[row] = b + sum_e norm_e * Thi@off_e  (self edge included in pairs)
// Lanes 0-31 process row A (8B of features per lane), lanes 32-63 row B.
// Loop runs max(itA,itB); exhausted half: j frozen, FMA guarded.
struct Pairs4 { int4 p0, p1, p2, p3; };

__device__ inline Pairs4 ldpairs(const int2* __restrict__ pairs, int j) {
    Pairs4 r;
    r.p0 = *(const int4*)(pairs + j);
    r.p1 = *(const int4*)(pairs + j + 2);
    r.p2 = *(const int4*)(pairs + j + 4);
    r.p3 = *(const int4*)(pairs + j + 6);
    return r;
}

template <int FOUT, bool SPLIT>
__global__ __launch_bounds__(256) void gather_k(const int* __restrict__ rowstart,
                                                const int2* __restrict__ pairs,
                                                const unsigned short* __restrict__ Thi,
                                                const float* __restrict__ bias,
                                                float* __restrict__ out,
                                                unsigned short* __restrict__ outHi,
                                                int N) {
    const int wave = threadIdx.x >> 6;
    const int lane = threadIdx.x & 63;
    const int half = lane >> 5;
    const int l = lane & 31;
    const int row = blockIdx.x * 8 + wave * 2 + half;
    const bool rowOK = row < N;
    const int rr = rowOK ? row : (N - 1);

    const int s0 = rowstart[rr];
    const int e = rowOK ? rowstart[rr + 1] : s0;  // inactive half: zero-trip
    const char* tbase = (const char*)Thi;

    int j = s0;
    Pairs4 P = ldpairs(pairs, j);

    if (FOUT == 128) {
        const int laneB = l * 8;  // 8 bytes = 4 bf16 features per lane
        float4 bb = *(const float4*)(bias + l * 4);
        float a0 = bb.x, a1 = bb.y, a2 = bb.z, a3 = bb.w;

        for (;;) {
            bool act = j < e;
            if (!__any(act)) break;
            uint2 m0 = *(const uint2*)(tbase + (unsigned)P.p0.x + laneB);
            uint2 m1 = *(const uint2*)(tbase + (unsigned)P.p0.z + laneB);
            uint2 m2 = *(const uint2*)(tbase + (unsigned)P.p1.x + laneB);
            uint2 m3 = *(const uint2*)(tbase + (unsigned)P.p1.z + laneB);
            uint2 m4 = *(const uint2*)(tbase + (unsigned)P.p2.x + laneB);
            uint2 m5 = *(const uint2*)(tbase + (unsigned)P.p2.z + laneB);
            uint2 m6 = *(const uint2*)(tbase + (unsigned)P.p3.x + laneB);
            uint2 m7 = *(const uint2*)(tbase + (unsigned)P.p3.z + laneB);
            const int jn = j + 8;
            Pairs4 Q = ldpairs(pairs, jn);  // slack keeps in-bounds
            if (act) {
                float n0 = __int_as_float(P.p0.y), n1 = __int_as_float(P.p0.w);
                float n2 = __int_as_float(P.p1.y), n3 = __int_as_float(P.p1.w);
                float n4 = __int_as_float(P.p2.y), n5 = __int_as_float(P.p2.w);
                float n6 = __int_as_float(P.p3.y), n7 = __int_as_float(P.p3.w);
                a0 += n0 * bf2f_lo(m0.x); a1 += n0 * bf2f_hi(m0.x);
                a2 += n0 * bf2f_lo(m0.y); a3 += n0 * bf2f_hi(m0.y);
                a0 += n1 * bf2f_lo(m1.x); a1 += n1 * bf2f_hi(m1.x);
                a2 += n1 * bf2f_lo(m1.y); a3 += n1 * bf2f_hi(m1.y);
                a0 += n2 * bf2f_lo(m2.x); a1 += n2 * bf2f_hi(m2.x);
                a2 += n2 * bf2f_lo(m2.y); a3 += n2 * bf2f_hi(m2.y);
                a0 += n3 * bf2f_lo(m3.x); a1 += n3 * bf2f_hi(m3.x);
                a2 += n3 * bf2f_lo(m3.y); a3 += n3 * bf2f_hi(m3.y);
                a0 += n4 * bf2f_lo(m4.x); a1 += n4 * bf2f_hi(m4.x);
                a2 += n4 * bf2f_lo(m4.y); a3 += n4 * bf2f_hi(m4.y);
                a0 += n5 * bf2f_lo(m5.x); a1 += n5 * bf2f_hi(m5.x);
                a2 += n5 * bf2f_lo(m5.y); a3 += n5 * bf2f_hi(m5.y);
                a0 += n6 * bf2f_lo(m6.x); a1 += n6 * bf2f_hi(m6.x);
                a2 += n6 * bf2f_lo(m6.y); a3 += n6 * bf2f_hi(m6.y);
                a0 += n7 * bf2f_lo(m7.x); a1 += n7 * bf2f_hi(m7.x);
                a2 += n7 * bf2f_lo(m7.y); a3 += n7 * bf2f_hi(m7.y);
                j = jn;
            }
            P = Q;
        }

        if (rowOK) {
            if (SPLIT) {
                ushort4 h;
                h.x = f2bf_rne(fmaxf(a0, 0.f));
                h.y = f2bf_rne(fmaxf(a1, 0.f));
                h.z = f2bf_rne(fmaxf(a2, 0.f));
                h.w = f2bf_rne(fmaxf(a3, 0.f));
                *(ushort4*)(outHi + (size_t)row * 128 + l * 4) = h;
            } else {
                float4 o; o.x = a0; o.y = a1; o.z = a2; o.w = a3;
                *(float4*)(out + (size_t)row * 128 + l * 4) = o;
            }
        }
    } else {  // FOUT == 64: rows are 128B; byte offset = off>>1; 4B per lane
        const int laneB = l * 4;
        float2 bb = *(const float2*)(bias + l * 2);
        float a0 = bb.x, a1 = bb.y;

        for (;;) {
            bool act = j < e;
            if (!__any(act)) break;
            unsigned m0 = *(const unsigned*)(tbase + ((unsigned)P.p0.x >> 1) + laneB);
            unsigned m1 = *(const unsigned*)(tbase + ((unsigned)P.p0.z >> 1) + laneB);
            unsigned m2 = *(const unsigned*)(tbase + ((unsigned)P.p1.x >> 1) + laneB);
            unsigned m3 = *(const unsigned*)(tbase + ((unsigned)P.p1.z >> 1) + laneB);
            unsigned m4 = *(const unsigned*)(tbase + ((unsigned)P.p2.x >> 1) + laneB);
            unsigned m5 = *(const unsigned*)(tbase + ((unsigned)P.p2.z >> 1) + laneB);
            unsigned m6 = *(const unsigned*)(tbase + ((unsigned)P.p3.x >> 1) + laneB);
            unsigned m7 = *(const unsigned*)(tbase + ((unsigned)P.p3.z >> 1) + laneB);
            const int jn = j + 8;
            Pairs4 Q = ldpairs(pairs, jn);
            if (act) {
                float n0 = __int_as_float(P.p0.y), n1 = __int_as_float(P.p0.w);
                float n2 = __int_as_float(P.p1.y), n3 = __int_as_float(P.p1.w);
                float n4 = __int_as_float(P.p2.y), n5 = __int_as_float(P.p2.w);
                float n6 = __int_as_float(P.p3.y), n7 = __int_as_float(P.p3.w);
                a0 += n0 * bf2f_lo(m0); a1 += n0 * bf2f_hi(m0);
                a0 += n1 * bf2f_lo(m1); a1 += n1 * bf2f_hi(m1);
                a0 += n2 * bf2f_lo(m2); a1 += n2 * bf2f_hi(m2);
                a0 += n3 * bf2f_lo(m3); a1 += n3 * bf2f_hi(m3);
                a0 += n4 * bf2f_lo(m4); a1 += n4 * bf2f_hi(m4);
                a0 += n5 * bf2f_lo(m5); a1 += n5 * bf2f_hi(m5);
                a0 += n6 * bf2f_lo(m6); a1 += n6 * bf2f_hi(m6);
                a0 += n7 * bf2f_lo(m7); a1 += n7 * bf2f_hi(m7);
                j = jn;
            }
            P = Q;
        }

        if (rowOK) {
            float2 o; o.x = a0; o.y = a1;
            *(float2*)(out + (size_t)row * 64 + l * 2) = o;
        }
    }
}

extern "C" void kernel_launch(void* const* d_in, const int* in_sizes, int n_in,
                              void* d_out, int out_size, void* d_ws, size_t ws_size,
                              hipStream_t stream) {
    const float* x  = (const float*)d_in[0];
    const int* eidx = (const int*)d_in[1];
    const float* W1 = (const float*)d_in[2];
    const float* b1 = (const float*)d_in[3];
    const float* W2 = (const float*)d_in[4];
    const float* b2 = (const float*)d_in[5];
    const float* W3 = (const float*)d_in[6];
    const float* b3 = (const float*)d_in[7];
    float* out = (float*)d_out;

    const int N = in_sizes[0] / IN_CH;
    const int E = in_sizes[1] / 2;
    const int* src = eidx;
    const int* dst = eidx + E;
    const int Npad = ((N + 127) / 128) * 128;
    const int nb = (N + 255) / 256;
    const int Emax = E + 8 * N + 24;  // self edges + 8-pad + prefetch slack

    auto align = [](size_t v) { return (v + 255) / 256 * 256; };
    char* p = (char*)d_ws;
    int* cnt = (int*)p;            p += align((size_t)N * 4);
    int* rowstart = (int*)p;       p += align((size_t)(N + 1) * 4);
    int* cur = (int*)p;            p += align((size_t)N * 4);
    int* bsum = (int*)p;           p += align((size_t)nb * 4);
    float* dinv = (float*)p;       p += align((size_t)N * 4);
    int2* pairs = (int2*)p;        p += align((size_t)Emax * 8);
    unsigned short* Ahi = (unsigned short*)p;  p += align((size_t)Npad * 128 * 2);
    unsigned short* Thi = (unsigned short*)p;  p += align((size_t)Npad * 128 * 2);
    unsigned short* W1h = (unsigned short*)p;  p += align(128 * 128 * 2);
    unsigned short* W2h = (unsigned short*)p;  p += align(128 * 128 * 2);
    unsigned short* W3h = (unsigned short*)p;

    // ---- CSR build (once; reused by all 3 layers) ----
    hipMemsetAsync(cnt, 0, (size_t)N * 4, stream);
    hipMemsetAsync(pairs, 0, (size_t)Emax * 8, stream);  // pad edges = (0,0)
    cnt_k<<<(E + 255) / 256, 256, 0, stream>>>(dst, cnt, E);
    scan1_k<<<nb, 256, 0, stream>>>(cnt, bsum, dinv, N);
    scan2_k<<<1, 512, 0, stream>>>(bsum, nb);
    scan3_k<<<nb, 256, 0, stream>>>(cnt, bsum, rowstart, cur, N);
    // partitioned fill: 8 dst-range passes, 4 edges/thread; + self edges + W conv
    const int chunks = (E + 1023) / 1024;
    const int fillBlocks = chunks * 8;
    const int selfBlocks = (N + 255) / 256;
    const int rangeSz = (N + 7) / 8;
    fill_conv_k<<<fillBlocks + selfBlocks + 160, 256, 0, stream>>>(
        src, dst, dinv, cur, pairs, E, N, fillBlocks, selfBlocks, rangeSz,
        W1, W2, W3, W1h, W2h, W3h);

    const int gemm_blocks = (N + 63) / 64;
    const int gather_blocks = (N + 7) / 8;

    // Layer 1 (A = x fp32, converted in-register)
    mfma_gemm<128, true><<<gemm_blocks, 256, 0, stream>>>(x, nullptr, W1h, Thi, N);
    gather_k<128, true><<<gather_blocks, 256, 0, stream>>>(rowstart, pairs, Thi,
                                                           b1, nullptr, Ahi, N);
    // Layer 2
    mfma_gemm<128, false><<<gemm_blocks, 256, 0, stream>>>(nullptr, Ahi, W2h, Thi, N);
    gather_k<128, true><<<gather_blocks, 256, 0, stream>>>(rowstart, pairs, Thi,
                                                           b2, nullptr, Ahi, N);
    // Layer 3
    mfma_gemm<64, false><<<gemm_blocks, 256, 0, stream>>>(nullptr, Ahi, W3h, Thi, N);
    gather_k<64, false><<<gather_blocks, 256, 0, stream>>>(rowstart, pairs, Thi,
                                                           b3, out, nullptr, N);
}